// Round 3
// baseline (58.197 us; speedup 1.0000x reference)
//
#include <hip/hip_runtime.h>
#include <math.h>

#define BB 8
#define LL 8192
#define CC 512
#define NCHUNK 256   // stat chunks per b (32 rows each)

#define H0_OFF (BB*CC)            // 4096
#define A_OFF  (H0_OFF + BB*CC*4) // 20480

#define F_ALPHA_BASE 1.2f
#define F_ALPHA_SCALE 0.3f
#define F_GRAPH_LAMBDA 0.3f
#define F_FUSION_BETA 0.1f
#define F_PRIOR_BETA 0.2f
#define F_LN_EPS 1e-5f

// ---------------- Kernel 1: partial stats over L ----------------
// grid = BB*NCHUNK = 2048 blocks (8/CU), block = 256. Block covers a 32-row
// slab; the two 128-thread halves each do 16 rows with float4 loads
// (1 KB/wave-instr), then combine via LDS so one chunk record is written.
// pbuf layout: [b][stat][chunk][c] so the reducer reads contiguous c.
__global__ __launch_bounds__(256) void k_stats(const float* __restrict__ res,
                                               float* __restrict__ pbuf) {
    __shared__ float comb[3][CC];   // 6 KB
    int b = blockIdx.x >> 8;
    int cb = blockIdx.x & 255;
    int sub = threadIdx.x >> 7;          // 0/1: rows [0,16) vs [16,32) of slab
    int c4 = (threadIdx.x & 127) * 4;
    const float* base = res + ((size_t)b * LL + (size_t)cb * 32 + sub * 16) * CC + c4;

    float s0 = 0.f, s1 = 0.f, s2 = 0.f, s3 = 0.f;
    float m0 = 0.f, m1 = 0.f, m2 = 0.f, m3 = 0.f;
    float q0 = 0.f, q1 = 0.f, q2 = 0.f, q3 = 0.f;
    #pragma unroll
    for (int r = 0; r < 16; r++) {
        float4 v = *(const float4*)(base + (size_t)r * CC);
        s0 += fabsf(v.x); s1 += fabsf(v.y); s2 += fabsf(v.z); s3 += fabsf(v.w);
        m0 = fmaxf(m0, fabsf(v.x)); m1 = fmaxf(m1, fabsf(v.y));
        m2 = fmaxf(m2, fabsf(v.z)); m3 = fmaxf(m3, fabsf(v.w));
        q0 = fmaf(v.x, v.x, q0); q1 = fmaf(v.y, v.y, q1);
        q2 = fmaf(v.z, v.z, q2); q3 = fmaf(v.w, v.w, q3);
    }
    if (sub == 1) {
        *(float4*)&comb[0][c4] = make_float4(s0, s1, s2, s3);
        *(float4*)&comb[1][c4] = make_float4(m0, m1, m2, m3);
        *(float4*)&comb[2][c4] = make_float4(q0, q1, q2, q3);
    }
    __syncthreads();
    if (sub == 0) {
        float4 cs = *(const float4*)&comb[0][c4];
        float4 cm = *(const float4*)&comb[1][c4];
        float4 cq = *(const float4*)&comb[2][c4];
        s0 += cs.x; s1 += cs.y; s2 += cs.z; s3 += cs.w;
        m0 = fmaxf(m0, cm.x); m1 = fmaxf(m1, cm.y);
        m2 = fmaxf(m2, cm.z); m3 = fmaxf(m3, cm.w);
        q0 += cq.x; q1 += cq.y; q2 += cq.z; q3 += cq.w;
        float* pb = pbuf + ((size_t)(b * 3) * NCHUNK + cb) * CC + c4;
        *(float4*)(pb)                        = make_float4(s0, s1, s2, s3);
        *(float4*)(pb + (size_t)NCHUNK * CC)     = make_float4(m0, m1, m2, m3);
        *(float4*)(pb + (size_t)2 * NCHUNK * CC) = make_float4(q0, q1, q2, q3);
    }
}

// ---------------- Kernel 2: finish reduction -> h0 ----------------
// 256 blocks x 256 threads. Block = (b, group of 16 c). Thread (coff, part):
// reduces 16 chunks for column c; shuffle over parts-in-wave, LDS over waves.
__global__ __launch_bounds__(256) void k_red(const float* __restrict__ pbuf,
                                             float* __restrict__ out) {
    __shared__ float red[4][3][16];
    int b = blockIdx.x >> 5;
    int c16g = blockIdx.x & 31;
    int coff = threadIdx.x & 15;
    int part = threadIdx.x >> 4;       // 0..15, 16 chunks each
    int c = c16g * 16 + coff;

    const float* pA = pbuf + ((size_t)(b * 3 + 0) * NCHUNK + part * 16) * CC + c;
    const float* pB = pbuf + ((size_t)(b * 3 + 1) * NCHUNK + part * 16) * CC + c;
    const float* pC = pbuf + ((size_t)(b * 3 + 2) * NCHUNK + part * 16) * CC + c;
    float sum = 0.f, mx = 0.f, sq = 0.f;
    #pragma unroll
    for (int i = 0; i < 16; i++) {
        sum += pA[(size_t)i * CC];
        mx = fmaxf(mx, pB[(size_t)i * CC]);
        sq += pC[(size_t)i * CC];
    }
    // combine the 4 parts living in this wave (tid bits 4,5)
    sum += __shfl_xor(sum, 16); sum += __shfl_xor(sum, 32);
    mx = fmaxf(mx, __shfl_xor(mx, 16)); mx = fmaxf(mx, __shfl_xor(mx, 32));
    sq += __shfl_xor(sq, 16); sq += __shfl_xor(sq, 32);
    int w = threadIdx.x >> 6;
    if ((threadIdx.x & 63) < 16) {
        red[w][0][coff] = sum;
        red[w][1][coff] = mx;
        red[w][2][coff] = sq;
    }
    __syncthreads();
    if (threadIdx.x < 16) {
        float ts = red[0][0][coff] + red[1][0][coff] + red[2][0][coff] + red[3][0][coff];
        float tm = fmaxf(fmaxf(red[0][1][coff], red[1][1][coff]),
                         fmaxf(red[2][1][coff], red[3][1][coff]));
        float tq = red[0][2][coff] + red[1][2][coff] + red[2][2][coff] + red[3][2][coff];
        float m = ts * (1.f / LL);
        float sqm = tq * (1.f / LL);
        float sd = sqrtf(fmaxf(sqm - m * m, 0.f));
        int g = b * CC + c16g * 16 + coff;
        *(float4*)(out + H0_OFF + (size_t)g * 4) = make_float4(m, tm, sd, sqm);
    }
}

// ---------------- Kernel 3: rows — adjacency softmax + msg + head ----------------
// grid = BB*(CC/8) = 512 blocks, block 256 (4 waves, TWO rows per wave).
// prior = relu(ne@ne^T) is computed per-wave into registers (ne is L1-resident).
__global__ __launch_bounds__(256) void k_rows(
    const float* __restrict__ h0,   // out + H0_OFF, [B][C][4]
    const float* __restrict__ ne,
    const float* __restrict__ Wl1, const float* __restrict__ bl1,
    const float* __restrict__ Wl2, const float* __restrict__ bl2,
    const float* __restrict__ Wg,  const float* __restrict__ bg,
    const float* __restrict__ Wq,  const float* __restrict__ bq,
    const float* __restrict__ Wk,  const float* __restrict__ bk,
    const float* __restrict__ Wf,  const float* __restrict__ bf,
    const float* __restrict__ Wo,  const float* __restrict__ bo,
    const float* __restrict__ lng, const float* __restrict__ lnb,
    float* __restrict__ out) {
    __shared__ float kls[8 * CC * 2];    // 32 KB, [t2][col] float2 planes
    __shared__ float hgls[8 * CC * 2];   // 32 KB
    int b = blockIdx.x >> 6;
    int rb = blockIdx.x & 63;
    int wid = threadIdx.x >> 6;
    int lane = threadIdx.x & 63;
    int row0 = rb * 8 + wid * 2;   // this wave's two rows

    // ---- prior rows into registers: pr[rr][j] = relu(ne[row]·ne[col]) ----
    float nr[2][16];
    #pragma unroll
    for (int rr = 0; rr < 2; rr++) {
        #pragma unroll
        for (int t = 0; t < 4; t++) {
            float4 v = *(const float4*)(ne + (size_t)(row0 + rr) * 16 + t * 4);
            nr[rr][4 * t] = v.x; nr[rr][4 * t + 1] = v.y;
            nr[rr][4 * t + 2] = v.z; nr[rr][4 * t + 3] = v.w;
        }
    }
    float pr[2][8];
    #pragma unroll
    for (int j = 0; j < 8; j++) {
        int col = lane + 64 * j;
        float d0 = 0.f, d1 = 0.f;
        #pragma unroll
        for (int t = 0; t < 4; t++) {
            float4 v = *(const float4*)(ne + (size_t)col * 16 + t * 4);
            d0 = fmaf(nr[0][4 * t], v.x, d0); d0 = fmaf(nr[0][4 * t + 1], v.y, d0);
            d0 = fmaf(nr[0][4 * t + 2], v.z, d0); d0 = fmaf(nr[0][4 * t + 3], v.w, d0);
            d1 = fmaf(nr[1][4 * t], v.x, d1); d1 = fmaf(nr[1][4 * t + 1], v.y, d1);
            d1 = fmaf(nr[1][4 * t + 2], v.z, d1); d1 = fmaf(nr[1][4 * t + 3], v.w, d1);
        }
        pr[0][j] = fmaxf(d0, 0.f);
        pr[1][j] = fmaxf(d1, 0.f);
    }

    // ---- stage k / h_graph_in projections for 2 columns per thread ----
    #pragma unroll
    for (int ccy = 0; ccy < 2; ccy++) {
        int col = threadIdx.x + ccy * 256;
        float4 hv = *(const float4*)(h0 + ((size_t)b * CC + col) * 4);
        float s[4] = {hv.x, hv.y, hv.z, hv.w};
        #pragma unroll
        for (int t2 = 0; t2 < 8; t2++) {
            float k0 = bk[2 * t2], k1 = bk[2 * t2 + 1];
            float g0 = bg[2 * t2], g1 = bg[2 * t2 + 1];
            #pragma unroll
            for (int j = 0; j < 4; j++) {
                k0 = fmaf(Wk[(2 * t2) * 4 + j], s[j], k0);
                k1 = fmaf(Wk[(2 * t2 + 1) * 4 + j], s[j], k1);
                g0 = fmaf(Wg[(2 * t2) * 4 + j], s[j], g0);
                g1 = fmaf(Wg[(2 * t2 + 1) * 4 + j], s[j], g1);
            }
            *(float2*)&kls[(t2 * CC + col) * 2] = make_float2(k0, k1);
            *(float2*)&hgls[(t2 * CC + col) * 2] = make_float2(g0, g1);
        }
    }
    __syncthreads();

    float s2[2][4];
    float qr[2][16];
    #pragma unroll
    for (int rr = 0; rr < 2; rr++) {
        float4 hr = *(const float4*)(h0 + ((size_t)b * CC + row0 + rr) * 4);
        s2[rr][0] = hr.x; s2[rr][1] = hr.y; s2[rr][2] = hr.z; s2[rr][3] = hr.w;
        #pragma unroll
        for (int i = 0; i < 16; i++) {
            float a = bq[i];
            #pragma unroll
            for (int j = 0; j < 4; j++) a = fmaf(Wq[i * 4 + j], s2[rr][j], a);
            qr[rr][i] = a;
        }
    }

    float sv[2][8];
    float mx0 = -1e30f, mx1 = -1e30f;
    #pragma unroll
    for (int j = 0; j < 8; j++) {
        int col = lane + 64 * j;
        float a0 = 0.f, a1 = 0.f;
        #pragma unroll
        for (int t2 = 0; t2 < 8; t2++) {
            float2 kk = *(const float2*)&kls[(t2 * CC + col) * 2];
            a0 = fmaf(qr[0][2 * t2], kk.x, a0);
            a0 = fmaf(qr[0][2 * t2 + 1], kk.y, a0);
            a1 = fmaf(qr[1][2 * t2], kk.x, a1);
            a1 = fmaf(qr[1][2 * t2 + 1], kk.y, a1);
        }
        float v0 = fmaxf(a0, 0.f) + F_PRIOR_BETA * pr[0][j] + (col == row0 ? 1.f : 0.f);
        float v1 = fmaxf(a1, 0.f) + F_PRIOR_BETA * pr[1][j] + (col == row0 + 1 ? 1.f : 0.f);
        sv[0][j] = v0; sv[1][j] = v1;
        mx0 = fmaxf(mx0, v0); mx1 = fmaxf(mx1, v1);
    }
    #pragma unroll
    for (int o = 32; o; o >>= 1) {
        mx0 = fmaxf(mx0, __shfl_xor(mx0, o));
        mx1 = fmaxf(mx1, __shfl_xor(mx1, o));
    }

    float ls0 = 0.f, ls1 = 0.f;
    float msg[2][16];
    #pragma unroll
    for (int h = 0; h < 16; h++) { msg[0][h] = 0.f; msg[1][h] = 0.f; }
    #pragma unroll
    for (int j = 0; j < 8; j++) {
        int col = lane + 64 * j;
        float e0 = expf(sv[0][j] - mx0);
        float e1 = expf(sv[1][j] - mx1);
        sv[0][j] = e0; sv[1][j] = e1;
        ls0 += e0; ls1 += e1;
        #pragma unroll
        for (int t2 = 0; t2 < 8; t2++) {
            float2 hh = *(const float2*)&hgls[(t2 * CC + col) * 2];
            msg[0][2 * t2]     = fmaf(e0, hh.x, msg[0][2 * t2]);
            msg[0][2 * t2 + 1] = fmaf(e0, hh.y, msg[0][2 * t2 + 1]);
            msg[1][2 * t2]     = fmaf(e1, hh.x, msg[1][2 * t2]);
            msg[1][2 * t2 + 1] = fmaf(e1, hh.y, msg[1][2 * t2 + 1]);
        }
    }
    #pragma unroll
    for (int o = 32; o; o >>= 1) {
        ls0 += __shfl_xor(ls0, o);
        ls1 += __shfl_xor(ls1, o);
    }
    float inv0 = 1.f / ls0, inv1 = 1.f / ls1;

    // A rows (coalesced)
    float* arow0 = out + A_OFF + ((size_t)b * CC + row0) * CC;
    #pragma unroll
    for (int j = 0; j < 8; j++) {
        arow0[lane + 64 * j]      = sv[0][j] * inv0;
        arow0[CC + lane + 64 * j] = sv[1][j] * inv1;
    }

    // full wave reduction of msg
    #pragma unroll
    for (int h = 0; h < 16; h++) {
        float v0 = msg[0][h], v1 = msg[1][h];
        #pragma unroll
        for (int o = 32; o; o >>= 1) {
            v0 += __shfl_xor(v0, o);
            v1 += __shfl_xor(v1, o);
        }
        msg[0][h] = v0 * inv0;
        msg[1][h] = v1 * inv1;
    }

    // ---- epilogue (redundant per lane; tiny) ----
    #pragma unroll
    for (int rr = 0; rr < 2; rr++) {
        int row = row0 + rr;
        float t1[16];
        #pragma unroll
        for (int i = 0; i < 16; i++) {
            float a = bl1[i];
            #pragma unroll
            for (int j = 0; j < 4; j++) a = fmaf(Wl1[i * 4 + j], s2[rr][j], a);
            t1[i] = fmaxf(a, 0.f);
        }
        float hvec[16];
        float mu = 0.f;
        #pragma unroll
        for (int h = 0; h < 16; h++) {
            float hl = bl2[h];
            #pragma unroll
            for (int j = 0; j < 16; j++) hl = fmaf(Wl2[h * 16 + j], t1[j], hl);
            float hgr = hgls[((h >> 1) * CC + row) * 2 + (h & 1)];
            float hg2 = hgr + F_GRAPH_LAMBDA * fmaxf(msg[rr][h], 0.f);
            float hv = hl + F_FUSION_BETA * hg2;
            hvec[h] = hv;
            mu += hv;
        }
        mu *= (1.f / 16.f);
        float var = 0.f;
        #pragma unroll
        for (int h = 0; h < 16; h++) { float d = hvec[h] - mu; var = fmaf(d, d, var); }
        var *= (1.f / 16.f);
        float istd = 1.f / sqrtf(var + F_LN_EPS);
        float hn[16];
        #pragma unroll
        for (int h = 0; h < 16; h++) hn[h] = (hvec[h] - mu) * istd * lng[h] + lnb[h];

        float acc2 = bo[0];
        #pragma unroll
        for (int o = 0; o < 16; o++) {
            float f = bf[o];
            #pragma unroll
            for (int t = 0; t < 16; t++) f = fmaf(Wf[o * 16 + t], hn[t], f);
            acc2 = fmaf(Wo[o], fmaxf(f, 0.f), acc2);
        }
        float alpha = F_ALPHA_BASE + F_ALPHA_SCALE * tanhf(acc2);
        if (lane == 0) out[(size_t)b * CC + row] = alpha;
    }
}

extern "C" void kernel_launch(void* const* d_in, const int* in_sizes, int n_in,
                              void* d_out, int out_size, void* d_ws, size_t ws_size,
                              hipStream_t stream) {
    const float* res = (const float*)d_in[0];
    const float* ne  = (const float*)d_in[1];
    const float* Wl1 = (const float*)d_in[2];
    const float* bl1 = (const float*)d_in[3];
    const float* Wl2 = (const float*)d_in[4];
    const float* bl2 = (const float*)d_in[5];
    const float* Wg  = (const float*)d_in[6];
    const float* bg  = (const float*)d_in[7];
    const float* Wq  = (const float*)d_in[8];
    const float* bq  = (const float*)d_in[9];
    const float* Wk  = (const float*)d_in[10];
    const float* bk  = (const float*)d_in[11];
    const float* Wf  = (const float*)d_in[12];
    const float* bf  = (const float*)d_in[13];
    const float* Wo  = (const float*)d_in[14];
    const float* bo  = (const float*)d_in[15];
    const float* lng = (const float*)d_in[16];
    const float* lnb = (const float*)d_in[17];
    float* out = (float*)d_out;
    float* pbuf = (float*)d_ws;   // [B][3][NCHUNK][C] = 12.6 MB

    k_stats<<<BB * NCHUNK, 256, 0, stream>>>(res, pbuf);
    k_red<<<BB * 32, 256, 0, stream>>>(pbuf, out);
    k_rows<<<BB * (CC / 8), 256, 0, stream>>>(out + H0_OFF, ne,
                                              Wl1, bl1, Wl2, bl2, Wg, bg, Wq, bq, Wk, bk,
                                              Wf, bf, Wo, bo, lng, lnb, out);
}